// Round 5
// baseline (369.816 us; speedup 1.0000x reference)
//
#include <hip/hip_runtime.h>

typedef __bf16 bf16;
typedef __attribute__((ext_vector_type(8))) __bf16 bf16x8;
typedef __attribute__((ext_vector_type(4))) __bf16 bf16x4;
typedef __attribute__((ext_vector_type(4))) float f32x4;

#define LOG2E 1.44269504088896340736f
#define QSCALE 0.18033688011112042f   // 0.125 * log2(e), folded into Q

// ---------------- Kernel P: fused prep ----------------
// sections: [0,2048) cast X; [2048,3072) Wq^T; [3072,3328) Wk^T; [3328,3584) Wv^T;
//           [3584,4608) Wo^T; [4608,4864) rope table; [4864,4866) mask bias + flags
__device__ inline void tr_tile(const float* __restrict__ in, bf16* __restrict__ out,
                               int R, int C, int bx, int by, int tid) {
    __shared__ float t[32][33];
    int tx = tid & 31, ty = tid >> 5;
    int rbase = by * 32, cbase = bx * 32;
#pragma unroll
    for (int i = 0; i < 4; i++) {
        int r = ty + i * 8;
        t[r][tx] = in[(size_t)(rbase + r) * C + cbase + tx];
    }
    __syncthreads();
#pragma unroll
    for (int i = 0; i < 4; i++) {
        int r = ty + i * 8;
        out[(size_t)(cbase + r) * R + rbase + tx] = (bf16)t[tx][r];
    }
}

__global__ __launch_bounds__(256) void prep_k(const float* __restrict__ X,
                                              const float* __restrict__ Wq,
                                              const float* __restrict__ Wk,
                                              const float* __restrict__ Wv,
                                              const float* __restrict__ Wo,
                                              const float* __restrict__ mask,
                                              bf16* __restrict__ Xb,
                                              bf16* __restrict__ WqT,
                                              bf16* __restrict__ WkT,
                                              bf16* __restrict__ WvT,
                                              bf16* __restrict__ WoT,
                                              float2* __restrict__ rt,
                                              float* __restrict__ Mb,
                                              int* __restrict__ mflags) {
    int blk = blockIdx.x, tid = threadIdx.x;
    if (blk < 2048) {
        int idx = (blk * 256 + tid) * 8;
        float4 a = *(const float4*)(X + idx);
        float4 b = *(const float4*)(X + idx + 4);
        bf16 v[8] = {(bf16)a.x, (bf16)a.y, (bf16)a.z, (bf16)a.w,
                     (bf16)b.x, (bf16)b.y, (bf16)b.z, (bf16)b.w};
        *(uint4*)(Xb + idx) = *(const uint4*)v;
    } else if (blk < 3072) {
        int t = blk - 2048; tr_tile(Wq, WqT, 1024, 1024, t & 31, t >> 5, tid);
    } else if (blk < 3328) {
        int t = blk - 3072; tr_tile(Wk, WkT, 1024, 256, t & 7, t >> 3, tid);
    } else if (blk < 3584) {
        int t = blk - 3328; tr_tile(Wv, WvT, 1024, 256, t & 7, t >> 3, tid);
    } else if (blk < 4608) {
        int t = blk - 3584; tr_tile(Wo, WoT, 1024, 1024, t & 31, t >> 5, tid);
    } else if (blk < 4864) {
        int idx = (blk - 4608) * 256 + tid;  // idx = s*32 + i, s<2048, i<32
        int s = idx >> 5, i = idx & 31;
        float inv = exp2f(-0.41524100370589830f * (float)i);  // 10000^(-i/32)
        float ang = (float)s * inv;
        rt[idx] = make_float2(cosf(ang), sinf(ang));
    } else {
        __shared__ int sflag;
        int b = blk - 4864;
        if (tid == 0) sflag = 1;
        __syncthreads();
        const float* mrow = mask + (size_t)b * 2048;
        int i0 = tid * 8;
        bool ones = true;
#pragma unroll
        for (int j = 0; j < 8; j++) {
            float m = mrow[i0 + j];
            if (m != 1.0f) ones = false;
            Mb[(size_t)b * 2048 + i0 + j] = (1.0f - m) * (-1e9f) * LOG2E;
        }
        if (!ones) sflag = 0;
        __syncthreads();
        if (tid == 0) mflags[b] = sflag;
    }
}

// ---------------- Kernel 0b: bf16 transpose per (b,kv): [2048][64] -> [64][2048] ----------------
__global__ __launch_bounds__(256) void vtrans_k(const unsigned short* __restrict__ in,
                                                unsigned short* __restrict__ out) {
    __shared__ unsigned short t[32][33];
    int z = blockIdx.z;
    const unsigned short* ip = in + (size_t)z * 2048 * 64;
    unsigned short* op = out + (size_t)z * 2048 * 64;
    int tx = threadIdx.x & 31, ty = threadIdx.x >> 5;
    int rbase = blockIdx.y * 32, cbase = blockIdx.x * 32;
#pragma unroll
    for (int i = 0; i < 4; i++) {
        int r = ty + i * 8;
        t[r][tx] = ip[(size_t)(rbase + r) * 64 + cbase + tx];
    }
    __syncthreads();
#pragma unroll
    for (int i = 0; i < 4; i++) {
        int r = ty + i * 8;
        op[(size_t)(cbase + r) * 2048 + rbase + tx] = t[tx][r];
    }
}

// ---------------- Kernel 1: fused QKV GEMM + bias + RoPE (table) + Q-prescale ----------------
__global__ __launch_bounds__(256) void qkv_gemm(const bf16* __restrict__ X,
                                                const bf16* __restrict__ WqT,
                                                const bf16* __restrict__ WkT,
                                                const bf16* __restrict__ WvT,
                                                const float* __restrict__ bq,
                                                const float* __restrict__ bk,
                                                const float* __restrict__ bv,
                                                const float2* __restrict__ rt,
                                                bf16* __restrict__ Qb,
                                                bf16* __restrict__ Kb,
                                                bf16* __restrict__ Vb) {
    int tt = blockIdx.x;
    int gy = blockIdx.y;
    const bf16* WT;
    const float* bias;
    bf16* dst;
    int mode, head;
    if (gy < 16)      { head = gy;      WT = WqT + (size_t)head * 64 * 1024; bias = bq + head * 64; dst = Qb; mode = 0; }
    else if (gy < 20) { head = gy - 16; WT = WkT + (size_t)head * 64 * 1024; bias = bk + head * 64; dst = Kb; mode = 1; }
    else              { head = gy - 20; WT = WvT + (size_t)head * 64 * 1024; bias = bv + head * 64; dst = Vb; mode = 2; }

    __shared__ unsigned short Xs[64 * 72];
    __shared__ unsigned short Ws[64 * 72];
    int tid = threadIdx.x;
    int w = tid >> 6, lane = tid & 63, l15 = lane & 15, quad = lane >> 4;

    f32x4 acc[4] = {};
    for (int k0 = 0; k0 < 1024; k0 += 64) {
#pragma unroll
        for (int i = tid; i < 512; i += 256) {
            int row = i >> 3, ch = i & 7;
            uint4 xv = *(const uint4*)(X + (size_t)(tt * 64 + row) * 1024 + k0 + ch * 8);
            *(uint4*)&Xs[row * 72 + ch * 8] = xv;
            uint4 wv = *(const uint4*)(WT + (size_t)row * 1024 + k0 + ch * 8);
            *(uint4*)&Ws[row * 72 + ch * 8] = wv;
        }
        __syncthreads();
        bf16x8 a0 = *(const bf16x8*)&Xs[(w * 16 + l15) * 72 + quad * 8];
        bf16x8 a1 = *(const bf16x8*)&Xs[(w * 16 + l15) * 72 + 32 + quad * 8];
#pragma unroll
        for (int c = 0; c < 4; c++) {
            bf16x8 b0 = *(const bf16x8*)&Ws[(c * 16 + l15) * 72 + quad * 8];
            bf16x8 b1 = *(const bf16x8*)&Ws[(c * 16 + l15) * 72 + 32 + quad * 8];
            acc[c] = __builtin_amdgcn_mfma_f32_16x16x32_bf16(a0, b0, acc[c], 0, 0, 0);
            acc[c] = __builtin_amdgcn_mfma_f32_16x16x32_bf16(a1, b1, acc[c], 0, 0, 0);
        }
        __syncthreads();
    }

#pragma unroll
    for (int r = 0; r < 4; r++) {
        int token = tt * 64 + w * 16 + quad * 4 + r;
        int b = token >> 11, s = token & 2047;
        float vals[4];
#pragma unroll
        for (int c = 0; c < 4; c++) vals[c] = acc[c][r] + bias[c * 16 + l15];
        if (mode <= 1) {  // RoPE for Q,K via table
#pragma unroll
            for (int c = 0; c < 2; c++) {
                float2 cs2 = rt[s * 32 + c * 16 + l15];
                float x1 = vals[c], x2 = vals[c + 2];
                vals[c]     = x1 * cs2.x - x2 * cs2.y;
                vals[c + 2] = x1 * cs2.y + x2 * cs2.x;
            }
        }
        if (mode == 0) {  // fold softmax scale (log2 domain) into Q
#pragma unroll
            for (int c = 0; c < 4; c++) vals[c] *= QSCALE;
        }
        size_t base;
        if (mode == 0) base = (((size_t)b * 16 + head) * 2048 + s) * 64;
        else           base = (((size_t)b * 4  + head) * 2048 + s) * 64;
#pragma unroll
        for (int c = 0; c < 4; c++) dst[base + c * 16 + l15] = (bf16)vals[c];
    }
}

// ---------------- Kernel 2: flash attention, barrier-free ----------------
// grid (32 qtiles, 16 heads, 2 batch), block 256 = 4 waves x 16 q-rows.
// K and V^T fragments are loaded global->VGPR directly (L2-resident, 512 KB per
// (b,kvh)); no LDS staging, no __syncthreads anywhere in the k-loop.
__global__ __launch_bounds__(256) void attn_k(const bf16* __restrict__ Qb,
                                              const bf16* __restrict__ Kb,
                                              const bf16* __restrict__ VbT,
                                              const float* __restrict__ Mb,
                                              const int* __restrict__ mflags,
                                              bf16* __restrict__ Ob) {
    int qt = blockIdx.x, h = blockIdx.y, b = blockIdx.z;
    int kvh = h >> 2;  // rep = 4

    __shared__ unsigned short Ps[4][16 * 72];  // per-wave P [q][key]

    int tid = threadIdx.x, w = tid >> 6, lane = tid & 63, l15 = lane & 15, quad = lane >> 4;

    const bool maskOnes = (mflags[b] != 0);

    // Q fragment (B-operand): lane n=l15 -> q, k=quad*8+j -> d. Q pre-scaled by QSCALE.
    size_t qbase = (((size_t)b * 16 + h) * 2048 + (size_t)qt * 64 + w * 16 + l15) * 64;
    bf16x8 qa0 = *(const bf16x8*)(Qb + qbase + quad * 8);
    bf16x8 qa1 = *(const bf16x8*)(Qb + qbase + 32 + quad * 8);

    f32x4 oacc[4] = {};
    float m2 = -1e30f, lsum = 0.f;  // per-lane state for q = l15

    // K A-fragment base: row = key (c*16+l15), col = d (quad*8 / +32)
    const bf16* kfrag = Kb + (((size_t)b * 4 + kvh) * 2048 + l15) * 64 + quad * 8;
    // V^T B-fragment base: row = d (c*16+l15), col = key (quad*8)
    const bf16* vfrag = VbT + (((size_t)b * 4 + kvh) * 64 + l15) * 2048 + quad * 8;
    const float* mrow = Mb + (size_t)b * 2048 + quad * 4;

    for (int kt = 0; kt < 32; kt++) {
        // ---- S^T = K·Q^T : A-fragments of K straight from global ----
        f32x4 sc[4];
#pragma unroll
        for (int c = 0; c < 4; c++) {
            const bf16* kp = kfrag + (size_t)(kt * 64 + c * 16) * 64;
            bf16x8 ka0 = *(const bf16x8*)(kp);
            bf16x8 ka1 = *(const bf16x8*)(kp + 32);
            f32x4 z = {};
            z = __builtin_amdgcn_mfma_f32_16x16x32_bf16(ka0, qa0, z, 0, 0, 0);
            z = __builtin_amdgcn_mfma_f32_16x16x32_bf16(ka1, qa1, z, 0, 0, 0);
            sc[c] = z;  // element (c,r): key = c*16+quad*4+r, q = l15
        }
        if (!maskOnes) {
#pragma unroll
            for (int c = 0; c < 4; c++) {
                f32x4 bias4 = *(const f32x4*)(mrow + kt * 64 + c * 16);
#pragma unroll
                for (int r = 0; r < 4; r++) sc[c][r] += bias4[r];
            }
        }

        // ---- online softmax over keys (per-lane q = l15) ----
        f32x4 m4 = sc[0];
#pragma unroll
        for (int c = 1; c < 4; c++)
#pragma unroll
            for (int r = 0; r < 4; r++) m4[r] = fmaxf(m4[r], sc[c][r]);
        float mx = fmaxf(fmaxf(m4[0], m4[1]), fmaxf(m4[2], m4[3]));
        mx = fmaxf(mx, __shfl_xor(mx, 16, 64));
        mx = fmaxf(mx, __shfl_xor(mx, 32, 64));

        if (__any(mx > m2)) {
            float mn = fmaxf(m2, mx);
            float alpha = exp2f(m2 - mn);
            m2 = mn;
            lsum *= alpha;
            float alpha_r[4];
#pragma unroll
            for (int r = 0; r < 4; r++) alpha_r[r] = __shfl(alpha, quad * 4 + r, 64);
#pragma unroll
            for (int c = 0; c < 4; c++)
#pragma unroll
                for (int r = 0; r < 4; r++) oacc[c][r] *= alpha_r[r];
        }

        float rs = 0.f;
#pragma unroll
        for (int c = 0; c < 4; c++)
#pragma unroll
            for (int r = 0; r < 4; r++) { sc[c][r] = exp2f(sc[c][r] - m2); rs += sc[c][r]; }
        rs += __shfl_xor(rs, 16, 64);
        rs += __shfl_xor(rs, 32, 64);
        lsum += rs;

        // ---- pack P (4 consecutive keys per (c,quad)) -> per-wave LDS, b64 writes ----
#pragma unroll
        for (int c = 0; c < 4; c++) {
            bf16x4 pv = {(bf16)sc[c][0], (bf16)sc[c][1], (bf16)sc[c][2], (bf16)sc[c][3]};
            *(bf16x4*)&Ps[w][l15 * 72 + c * 16 + quad * 4] = pv;
        }

        // ---- O += P·V : A = P[q][key] (same-wave LDS, lgkmcnt only), B = V^T global ----
        bf16x8 pa0 = *(const bf16x8*)&Ps[w][l15 * 72 + quad * 8];
        bf16x8 pa1 = *(const bf16x8*)&Ps[w][l15 * 72 + 32 + quad * 8];
#pragma unroll
        for (int c = 0; c < 4; c++) {
            const bf16* vp = vfrag + (size_t)c * 16 * 2048 + kt * 64;
            bf16x8 vb0 = *(const bf16x8*)(vp);
            bf16x8 vb1 = *(const bf16x8*)(vp + 32);
            oacc[c] = __builtin_amdgcn_mfma_f32_16x16x32_bf16(pa0, vb0, oacc[c], 0, 0, 0);
            oacc[c] = __builtin_amdgcn_mfma_f32_16x16x32_bf16(pa1, vb1, oacc[c], 0, 0, 0);
        }
    }

    // epilogue: O[b][q][h*64+d] = oacc / lsum(q)
    float linv[4];
#pragma unroll
    for (int r = 0; r < 4; r++) linv[r] = 1.0f / __shfl(lsum, quad * 4 + r, 64);
#pragma unroll
    for (int r = 0; r < 4; r++) {
        int q = qt * 64 + w * 16 + quad * 4 + r;
        size_t base = ((size_t)b * 2048 + q) * 1024 + h * 64;
#pragma unroll
        for (int c = 0; c < 4; c++) Ob[base + c * 16 + l15] = (bf16)(oacc[c][r] * linv[r]);
    }
}

// ---------------- Kernel 3: O projection (fp32 output) ----------------
__global__ __launch_bounds__(256) void oproj_gemm(const bf16* __restrict__ A,
                                                  const bf16* __restrict__ WoT,
                                                  const float* __restrict__ bo,
                                                  float* __restrict__ out) {
    int tt = blockIdx.x, gy = blockIdx.y;
    const bf16* WT = WoT + (size_t)gy * 64 * 1024;

    __shared__ unsigned short Xs[64 * 72];
    __shared__ unsigned short Ws[64 * 72];
    int tid = threadIdx.x;
    int w = tid >> 6, lane = tid & 63, l15 = lane & 15, quad = lane >> 4;

    f32x4 acc[4] = {};
    for (int k0 = 0; k0 < 1024; k0 += 64) {
#pragma unroll
        for (int i = tid; i < 512; i += 256) {
            int row = i >> 3, ch = i & 7;
            uint4 xv = *(const uint4*)(A + (size_t)(tt * 64 + row) * 1024 + k0 + ch * 8);
            *(uint4*)&Xs[row * 72 + ch * 8] = xv;
            uint4 wv = *(const uint4*)(WT + (size_t)row * 1024 + k0 + ch * 8);
            *(uint4*)&Ws[row * 72 + ch * 8] = wv;
        }
        __syncthreads();
        bf16x8 a0 = *(const bf16x8*)&Xs[(w * 16 + l15) * 72 + quad * 8];
        bf16x8 a1 = *(const bf16x8*)&Xs[(w * 16 + l15) * 72 + 32 + quad * 8];
#pragma unroll
        for (int c = 0; c < 4; c++) {
            bf16x8 b0 = *(const bf16x8*)&Ws[(c * 16 + l15) * 72 + quad * 8];
            bf16x8 b1 = *(const bf16x8*)&Ws[(c * 16 + l15) * 72 + 32 + quad * 8];
            acc[c] = __builtin_amdgcn_mfma_f32_16x16x32_bf16(a0, b0, acc[c], 0, 0, 0);
            acc[c] = __builtin_amdgcn_mfma_f32_16x16x32_bf16(a1, b1, acc[c], 0, 0, 0);
        }
        __syncthreads();
    }
#pragma unroll
    for (int r = 0; r < 4; r++) {
        int token = tt * 64 + w * 16 + quad * 4 + r;
#pragma unroll
        for (int c = 0; c < 4; c++) {
            int n = gy * 64 + c * 16 + l15;
            out[(size_t)token * 1024 + n] = acc[c][r] + bo[n];
        }
    }
}

// ---------------- launch ----------------
extern "C" void kernel_launch(void* const* d_in, const int* in_sizes, int n_in,
                              void* d_out, int out_size, void* d_ws, size_t ws_size,
                              hipStream_t stream) {
    const float* X    = (const float*)d_in[0];
    const float* mask = (const float*)d_in[1];
    const float* Wq   = (const float*)d_in[2];
    const float* bq   = (const float*)d_in[3];
    const float* Wk   = (const float*)d_in[4];
    const float* bk   = (const float*)d_in[5];
    const float* Wv   = (const float*)d_in[6];
    const float* bv   = (const float*)d_in[7];
    const float* Wo   = (const float*)d_in[8];
    const float* bo   = (const float*)d_in[9];
    float* out = (float*)d_out;
    bf16* ws  = (bf16*)d_ws;

    // workspace layout (bf16 elements)
    bf16* Xb  = ws;                       // 4096x1024 (dead after qkv_gemm -> reused for VbT)
    bf16* WqT = Xb + (size_t)4096 * 1024; // 1024x1024
    bf16* WkT = WqT + 1024 * 1024;        // 256x1024
    bf16* WvT = WkT + 256 * 1024;         // 256x1024
    bf16* WoT = WvT + 256 * 1024;         // 1024x1024
    bf16* Qb  = WoT + 1024 * 1024;        // [2][16][2048][64]
    bf16* Kb  = Qb + (size_t)2 * 16 * 2048 * 64;  // [2][4][2048][64]
    bf16* Vb  = Kb + (size_t)2 * 4 * 2048 * 64;   // [2][4][2048][64]
    bf16* Ab  = Vb + (size_t)2 * 4 * 2048 * 64;   // [2][2048][1024]
    float2* rt = (float2*)(Ab + (size_t)2 * 2048 * 1024);  // [2048][32] cos/sin
    float* Mb  = (float*)(rt + 2048 * 32);        // [2][2048] log2-domain mask bias
    int* mflags = (int*)(Mb + 2 * 2048);          // [2]
    bf16* VbT = Xb;                               // [2][4][64][2048]

    prep_k<<<4866, 256, 0, stream>>>(X, Wq, Wk, Wv, Wo, mask, Xb, WqT, WkT, WvT, WoT, rt, Mb, mflags);
    qkv_gemm<<<dim3(64, 24), 256, 0, stream>>>(Xb, WqT, WkT, WvT, bq, bk, bv, rt, Qb, Kb, Vb);
    vtrans_k<<<dim3(2, 64, 8), 256, 0, stream>>>((const unsigned short*)Vb, (unsigned short*)VbT);
    attn_k<<<dim3(32, 16, 2), 256, 0, stream>>>(Qb, Kb, VbT, Mb, mflags, Ab);
    oproj_gemm<<<dim3(64, 16), 256, 0, stream>>>(Ab, WoT, bo, out);
}

// Round 6
// 228.889 us; speedup vs baseline: 1.6157x; 1.6157x over previous
//
#include <hip/hip_runtime.h>

typedef __bf16 bf16;
typedef __attribute__((ext_vector_type(8))) __bf16 bf16x8;
typedef __attribute__((ext_vector_type(4))) __bf16 bf16x4;
typedef __attribute__((ext_vector_type(4))) float f32x4;

#define LOG2E 1.44269504088896340736f
#define QSCALE 0.18033688011112042f   // 0.125 * log2(e), folded into Q

// ---------------- Kernel P: fused prep ----------------
__device__ inline void tr_tile(const float* __restrict__ in, bf16* __restrict__ out,
                               int R, int C, int bx, int by, int tid) {
    __shared__ float t[32][33];
    int tx = tid & 31, ty = tid >> 5;
    int rbase = by * 32, cbase = bx * 32;
#pragma unroll
    for (int i = 0; i < 4; i++) {
        int r = ty + i * 8;
        t[r][tx] = in[(size_t)(rbase + r) * C + cbase + tx];
    }
    __syncthreads();
#pragma unroll
    for (int i = 0; i < 4; i++) {
        int r = ty + i * 8;
        out[(size_t)(cbase + r) * R + rbase + tx] = (bf16)t[tx][r];
    }
}

__global__ __launch_bounds__(256) void prep_k(const float* __restrict__ X,
                                              const float* __restrict__ Wq,
                                              const float* __restrict__ Wk,
                                              const float* __restrict__ Wv,
                                              const float* __restrict__ Wo,
                                              const float* __restrict__ mask,
                                              bf16* __restrict__ Xb,
                                              bf16* __restrict__ WqT,
                                              bf16* __restrict__ WkT,
                                              bf16* __restrict__ WvT,
                                              bf16* __restrict__ WoT,
                                              float2* __restrict__ rt,
                                              float* __restrict__ Mb,
                                              int* __restrict__ mflags) {
    int blk = blockIdx.x, tid = threadIdx.x;
    if (blk < 2048) {
        int idx = (blk * 256 + tid) * 8;
        float4 a = *(const float4*)(X + idx);
        float4 b = *(const float4*)(X + idx + 4);
        bf16 v[8] = {(bf16)a.x, (bf16)a.y, (bf16)a.z, (bf16)a.w,
                     (bf16)b.x, (bf16)b.y, (bf16)b.z, (bf16)b.w};
        *(uint4*)(Xb + idx) = *(const uint4*)v;
    } else if (blk < 3072) {
        int t = blk - 2048; tr_tile(Wq, WqT, 1024, 1024, t & 31, t >> 5, tid);
    } else if (blk < 3328) {
        int t = blk - 3072; tr_tile(Wk, WkT, 1024, 256, t & 7, t >> 3, tid);
    } else if (blk < 3584) {
        int t = blk - 3328; tr_tile(Wv, WvT, 1024, 256, t & 7, t >> 3, tid);
    } else if (blk < 4608) {
        int t = blk - 3584; tr_tile(Wo, WoT, 1024, 1024, t & 31, t >> 5, tid);
    } else if (blk < 4864) {
        int idx = (blk - 4608) * 256 + tid;  // idx = s*32 + i
        int s = idx >> 5, i = idx & 31;
        float inv = exp2f(-0.41524100370589830f * (float)i);  // 10000^(-i/32)
        float ang = (float)s * inv;
        rt[idx] = make_float2(cosf(ang), sinf(ang));
    } else {
        __shared__ int sflag;
        int b = blk - 4864;
        if (tid == 0) sflag = 1;
        __syncthreads();
        const float* mrow = mask + (size_t)b * 2048;
        int i0 = tid * 8;
        bool ones = true;
#pragma unroll
        for (int j = 0; j < 8; j++) {
            float m = mrow[i0 + j];
            if (m != 1.0f) ones = false;
            Mb[(size_t)b * 2048 + i0 + j] = (1.0f - m) * (-1e9f) * LOG2E;
        }
        if (!ones) sflag = 0;
        __syncthreads();
        if (tid == 0) mflags[b] = sflag;
    }
}

// ---------------- Kernel 0b: bf16 transpose per (b,kv): [2048][64] -> [64][2048] ----------------
__global__ __launch_bounds__(256) void vtrans_k(const unsigned short* __restrict__ in,
                                                unsigned short* __restrict__ out) {
    __shared__ unsigned short t[32][33];
    int z = blockIdx.z;
    const unsigned short* ip = in + (size_t)z * 2048 * 64;
    unsigned short* op = out + (size_t)z * 2048 * 64;
    int tx = threadIdx.x & 31, ty = threadIdx.x >> 5;
    int rbase = blockIdx.y * 32, cbase = blockIdx.x * 32;
#pragma unroll
    for (int i = 0; i < 4; i++) {
        int r = ty + i * 8;
        t[r][tx] = ip[(size_t)(rbase + r) * 64 + cbase + tx];
    }
    __syncthreads();
#pragma unroll
    for (int i = 0; i < 4; i++) {
        int r = ty + i * 8;
        op[(size_t)(cbase + r) * 2048 + rbase + tx] = t[tx][r];
    }
}

// ---------------- Kernel 1: fused QKV GEMM + bias + RoPE (table) + Q-prescale ----------------
__global__ __launch_bounds__(256) void qkv_gemm(const bf16* __restrict__ X,
                                                const bf16* __restrict__ WqT,
                                                const bf16* __restrict__ WkT,
                                                const bf16* __restrict__ WvT,
                                                const float* __restrict__ bq,
                                                const float* __restrict__ bk,
                                                const float* __restrict__ bv,
                                                const float2* __restrict__ rt,
                                                bf16* __restrict__ Qb,
                                                bf16* __restrict__ Kb,
                                                bf16* __restrict__ Vb) {
    int tt = blockIdx.x;
    int gy = blockIdx.y;
    const bf16* WT;
    const float* bias;
    bf16* dst;
    int mode, head;
    if (gy < 16)      { head = gy;      WT = WqT + (size_t)head * 64 * 1024; bias = bq + head * 64; dst = Qb; mode = 0; }
    else if (gy < 20) { head = gy - 16; WT = WkT + (size_t)head * 64 * 1024; bias = bk + head * 64; dst = Kb; mode = 1; }
    else              { head = gy - 20; WT = WvT + (size_t)head * 64 * 1024; bias = bv + head * 64; dst = Vb; mode = 2; }

    __shared__ unsigned short Xs[64 * 72];
    __shared__ unsigned short Ws[64 * 72];
    int tid = threadIdx.x;
    int w = tid >> 6, lane = tid & 63, l15 = lane & 15, quad = lane >> 4;

    f32x4 acc[4] = {};
    for (int k0 = 0; k0 < 1024; k0 += 64) {
#pragma unroll
        for (int i = tid; i < 512; i += 256) {
            int row = i >> 3, ch = i & 7;
            uint4 xv = *(const uint4*)(X + (size_t)(tt * 64 + row) * 1024 + k0 + ch * 8);
            *(uint4*)&Xs[row * 72 + ch * 8] = xv;
            uint4 wv = *(const uint4*)(WT + (size_t)row * 1024 + k0 + ch * 8);
            *(uint4*)&Ws[row * 72 + ch * 8] = wv;
        }
        __syncthreads();
        bf16x8 a0 = *(const bf16x8*)&Xs[(w * 16 + l15) * 72 + quad * 8];
        bf16x8 a1 = *(const bf16x8*)&Xs[(w * 16 + l15) * 72 + 32 + quad * 8];
#pragma unroll
        for (int c = 0; c < 4; c++) {
            bf16x8 b0 = *(const bf16x8*)&Ws[(c * 16 + l15) * 72 + quad * 8];
            bf16x8 b1 = *(const bf16x8*)&Ws[(c * 16 + l15) * 72 + 32 + quad * 8];
            acc[c] = __builtin_amdgcn_mfma_f32_16x16x32_bf16(a0, b0, acc[c], 0, 0, 0);
            acc[c] = __builtin_amdgcn_mfma_f32_16x16x32_bf16(a1, b1, acc[c], 0, 0, 0);
        }
        __syncthreads();
    }

#pragma unroll
    for (int r = 0; r < 4; r++) {
        int token = tt * 64 + w * 16 + quad * 4 + r;
        int b = token >> 11, s = token & 2047;
        float vals[4];
#pragma unroll
        for (int c = 0; c < 4; c++) vals[c] = acc[c][r] + bias[c * 16 + l15];
        if (mode <= 1) {  // RoPE via table
#pragma unroll
            for (int c = 0; c < 2; c++) {
                float2 cs2 = rt[s * 32 + c * 16 + l15];
                float x1 = vals[c], x2 = vals[c + 2];
                vals[c]     = x1 * cs2.x - x2 * cs2.y;
                vals[c + 2] = x1 * cs2.y + x2 * cs2.x;
            }
        }
        if (mode == 0) {
#pragma unroll
            for (int c = 0; c < 4; c++) vals[c] *= QSCALE;
        }
        size_t base;
        if (mode == 0) base = (((size_t)b * 16 + head) * 2048 + s) * 64;
        else           base = (((size_t)b * 4  + head) * 2048 + s) * 64;
#pragma unroll
        for (int c = 0; c < 4; c++) dst[base + c * 16 + l15] = (bf16)vals[c];
    }
}

// ---------------- Kernel 2: flash attention (S^T, LDS staging, 32q/wave) ----------------
// grid (16 qtiles of 128, 16 heads, 2 batch), block 256 = 4 waves.
// Wave w handles q rows [qt*128 + w*32, +32) as 2 groups of 16.
// K/V fragments read from LDS ONCE per wave-kt into regs, reused for both groups.
__global__ __launch_bounds__(256) void attn_k(const bf16* __restrict__ Qb,
                                              const bf16* __restrict__ Kb,
                                              const bf16* __restrict__ VbT,
                                              const float* __restrict__ Mb,
                                              const int* __restrict__ mflags,
                                              bf16* __restrict__ Ob) {
    int qt = blockIdx.x, h = blockIdx.y, b = blockIdx.z;
    int kvh = h >> 2;  // rep = 4

    __shared__ unsigned short Ks[64 * 72];      // [key][d]
    __shared__ unsigned short Vs[64 * 72];      // [d][key] (from VbT)
    __shared__ unsigned short Ps[4][32 * 72];   // per-wave P [q(32)][key]

    int tid = threadIdx.x, w = tid >> 6, lane = tid & 63, l15 = lane & 15, quad = lane >> 4;

    const bool maskOnes = (mflags[b] != 0);

    // Q fragments (B-operand) for 2 groups; Q pre-scaled by QSCALE (log2 domain)
    bf16x8 qa[2][2];
#pragma unroll
    for (int g = 0; g < 2; g++) {
        size_t qbase = (((size_t)b * 16 + h) * 2048 + (size_t)qt * 128 + w * 32 + g * 16 + l15) * 64;
        qa[g][0] = *(const bf16x8*)(Qb + qbase + quad * 8);
        qa[g][1] = *(const bf16x8*)(Qb + qbase + 32 + quad * 8);
    }

    f32x4 oacc[2][4] = {};
    float m2[2] = {-1e30f, -1e30f}, lsum[2] = {0.f, 0.f};

    size_t kRow = ((size_t)b * 4 + kvh) * 2048;  // row base in Kb
    size_t vRow = ((size_t)b * 4 + kvh) * 64;    // row base in VbT
    const float* mrow = Mb + (size_t)b * 2048 + quad * 4;

    for (int kt = 0; kt < 32; kt++) {
#pragma unroll
        for (int it = 0; it < 2; it++) {
            int i = tid + it * 256;
            int row = i >> 3, cg = i & 7;
            uint4 kv4 = *(const uint4*)(Kb + (kRow + kt * 64 + row) * 64 + cg * 8);
            *(uint4*)&Ks[row * 72 + cg * 8] = kv4;
            uint4 vv4 = *(const uint4*)(VbT + (vRow + row) * 2048 + kt * 64 + cg * 8);
            *(uint4*)&Vs[row * 72 + cg * 8] = vv4;
        }
        __syncthreads();

        // ---- K A-fragments: read once, reuse for both q-groups ----
        bf16x8 ka[4][2];
#pragma unroll
        for (int c = 0; c < 4; c++) {
            ka[c][0] = *(const bf16x8*)&Ks[(c * 16 + l15) * 72 + quad * 8];
            ka[c][1] = *(const bf16x8*)&Ks[(c * 16 + l15) * 72 + 32 + quad * 8];
        }

        // ---- S^T = K·Q^T per group ----
        f32x4 sc[2][4];
#pragma unroll
        for (int g = 0; g < 2; g++)
#pragma unroll
            for (int c = 0; c < 4; c++) {
                f32x4 z = {};
                z = __builtin_amdgcn_mfma_f32_16x16x32_bf16(ka[c][0], qa[g][0], z, 0, 0, 0);
                z = __builtin_amdgcn_mfma_f32_16x16x32_bf16(ka[c][1], qa[g][1], z, 0, 0, 0);
                sc[g][c] = z;  // (c,r): key = c*16+quad*4+r, q = group g, lane l15
            }
        if (!maskOnes) {
#pragma unroll
            for (int c = 0; c < 4; c++) {
                f32x4 bias4 = *(const f32x4*)(mrow + kt * 64 + c * 16);
#pragma unroll
                for (int r = 0; r < 4; r++) { sc[0][c][r] += bias4[r]; sc[1][c][r] += bias4[r]; }
            }
        }

        // ---- online softmax per group (per-lane q) ----
#pragma unroll
        for (int g = 0; g < 2; g++) {
            f32x4 m4 = sc[g][0];
#pragma unroll
            for (int c = 1; c < 4; c++)
#pragma unroll
                for (int r = 0; r < 4; r++) m4[r] = fmaxf(m4[r], sc[g][c][r]);
            float mx = fmaxf(fmaxf(m4[0], m4[1]), fmaxf(m4[2], m4[3]));
            mx = fmaxf(mx, __shfl_xor(mx, 16, 64));
            mx = fmaxf(mx, __shfl_xor(mx, 32, 64));

            if (__any(mx > m2[g])) {
                float mn = fmaxf(m2[g], mx);
                float alpha = exp2f(m2[g] - mn);
                m2[g] = mn;
                lsum[g] *= alpha;
                float alpha_r[4];
#pragma unroll
                for (int r = 0; r < 4; r++) alpha_r[r] = __shfl(alpha, quad * 4 + r, 64);
#pragma unroll
                for (int c = 0; c < 4; c++)
#pragma unroll
                    for (int r = 0; r < 4; r++) oacc[g][c][r] *= alpha_r[r];
            }

            float rs = 0.f;
#pragma unroll
            for (int c = 0; c < 4; c++)
#pragma unroll
                for (int r = 0; r < 4; r++) { sc[g][c][r] = exp2f(sc[g][c][r] - m2[g]); rs += sc[g][c][r]; }
            rs += __shfl_xor(rs, 16, 64);
            rs += __shfl_xor(rs, 32, 64);
            lsum[g] += rs;

            // pack P (4 consecutive keys per (c,quad)) -> per-wave LDS
#pragma unroll
            for (int c = 0; c < 4; c++) {
                bf16x4 pv = {(bf16)sc[g][c][0], (bf16)sc[g][c][1], (bf16)sc[g][c][2], (bf16)sc[g][c][3]};
                *(bf16x4*)&Ps[w][(g * 16 + l15) * 72 + c * 16 + quad * 4] = pv;
            }
        }

        // ---- V B-fragments: read once, reuse for both groups ----
        bf16x8 vb[4][2];
#pragma unroll
        for (int c = 0; c < 4; c++) {
            vb[c][0] = *(const bf16x8*)&Vs[(c * 16 + l15) * 72 + quad * 8];
            vb[c][1] = *(const bf16x8*)&Vs[(c * 16 + l15) * 72 + 32 + quad * 8];
        }
        // P A-fragments (same-wave LDS round-trip, lgkmcnt only)
        bf16x8 pa[2][2];
#pragma unroll
        for (int g = 0; g < 2; g++) {
            pa[g][0] = *(const bf16x8*)&Ps[w][(g * 16 + l15) * 72 + quad * 8];
            pa[g][1] = *(const bf16x8*)&Ps[w][(g * 16 + l15) * 72 + 32 + quad * 8];
        }
#pragma unroll
        for (int g = 0; g < 2; g++)
#pragma unroll
            for (int c = 0; c < 4; c++) {
                oacc[g][c] = __builtin_amdgcn_mfma_f32_16x16x32_bf16(pa[g][0], vb[c][0], oacc[g][c], 0, 0, 0);
                oacc[g][c] = __builtin_amdgcn_mfma_f32_16x16x32_bf16(pa[g][1], vb[c][1], oacc[g][c], 0, 0, 0);
            }
        __syncthreads();  // Ks/Vs reads done before next staging overwrites
    }

    // epilogue
#pragma unroll
    for (int g = 0; g < 2; g++) {
        float linv[4];
#pragma unroll
        for (int r = 0; r < 4; r++) linv[r] = 1.0f / __shfl(lsum[g], quad * 4 + r, 64);
#pragma unroll
        for (int r = 0; r < 4; r++) {
            int q = qt * 128 + w * 32 + g * 16 + quad * 4 + r;
            size_t base = ((size_t)b * 2048 + q) * 1024 + h * 64;
#pragma unroll
            for (int c = 0; c < 4; c++) Ob[base + c * 16 + l15] = (bf16)(oacc[g][c][r] * linv[r]);
        }
    }
}

// ---------------- Kernel 3: O projection (fp32 output) ----------------
__global__ __launch_bounds__(256) void oproj_gemm(const bf16* __restrict__ A,
                                                  const bf16* __restrict__ WoT,
                                                  const float* __restrict__ bo,
                                                  float* __restrict__ out) {
    int tt = blockIdx.x, gy = blockIdx.y;
    const bf16* WT = WoT + (size_t)gy * 64 * 1024;

    __shared__ unsigned short Xs[64 * 72];
    __shared__ unsigned short Ws[64 * 72];
    int tid = threadIdx.x;
    int w = tid >> 6, lane = tid & 63, l15 = lane & 15, quad = lane >> 4;

    f32x4 acc[4] = {};
    for (int k0 = 0; k0 < 1024; k0 += 64) {
#pragma unroll
        for (int i = tid; i < 512; i += 256) {
            int row = i >> 3, ch = i & 7;
            uint4 xv = *(const uint4*)(A + (size_t)(tt * 64 + row) * 1024 + k0 + ch * 8);
            *(uint4*)&Xs[row * 72 + ch * 8] = xv;
            uint4 wv = *(const uint4*)(WT + (size_t)row * 1024 + k0 + ch * 8);
            *(uint4*)&Ws[row * 72 + ch * 8] = wv;
        }
        __syncthreads();
        bf16x8 a0 = *(const bf16x8*)&Xs[(w * 16 + l15) * 72 + quad * 8];
        bf16x8 a1 = *(const bf16x8*)&Xs[(w * 16 + l15) * 72 + 32 + quad * 8];
#pragma unroll
        for (int c = 0; c < 4; c++) {
            bf16x8 b0 = *(const bf16x8*)&Ws[(c * 16 + l15) * 72 + quad * 8];
            bf16x8 b1 = *(const bf16x8*)&Ws[(c * 16 + l15) * 72 + 32 + quad * 8];
            acc[c] = __builtin_amdgcn_mfma_f32_16x16x32_bf16(a0, b0, acc[c], 0, 0, 0);
            acc[c] = __builtin_amdgcn_mfma_f32_16x16x32_bf16(a1, b1, acc[c], 0, 0, 0);
        }
        __syncthreads();
    }
#pragma unroll
    for (int r = 0; r < 4; r++) {
        int token = tt * 64 + w * 16 + quad * 4 + r;
#pragma unroll
        for (int c = 0; c < 4; c++) {
            int n = gy * 64 + c * 16 + l15;
            out[(size_t)token * 1024 + n] = acc[c][r] + bo[n];
        }
    }
}

// ---------------- launch ----------------
extern "C" void kernel_launch(void* const* d_in, const int* in_sizes, int n_in,
                              void* d_out, int out_size, void* d_ws, size_t ws_size,
                              hipStream_t stream) {
    const float* X    = (const float*)d_in[0];
    const float* mask = (const float*)d_in[1];
    const float* Wq   = (const float*)d_in[2];
    const float* bq   = (const float*)d_in[3];
    const float* Wk   = (const float*)d_in[4];
    const float* bk   = (const float*)d_in[5];
    const float* Wv   = (const float*)d_in[6];
    const float* bv   = (const float*)d_in[7];
    const float* Wo   = (const float*)d_in[8];
    const float* bo   = (const float*)d_in[9];
    float* out = (float*)d_out;
    bf16* ws  = (bf16*)d_ws;

    bf16* Xb  = ws;                       // 4096x1024 (reused for VbT after qkv)
    bf16* WqT = Xb + (size_t)4096 * 1024;
    bf16* WkT = WqT + 1024 * 1024;
    bf16* WvT = WkT + 256 * 1024;
    bf16* WoT = WvT + 256 * 1024;
    bf16* Qb  = WoT + 1024 * 1024;
    bf16* Kb  = Qb + (size_t)2 * 16 * 2048 * 64;
    bf16* Vb  = Kb + (size_t)2 * 4 * 2048 * 64;
    bf16* Ab  = Vb + (size_t)2 * 4 * 2048 * 64;
    float2* rt = (float2*)(Ab + (size_t)2 * 2048 * 1024);
    float* Mb  = (float*)(rt + 2048 * 32);
    int* mflags = (int*)(Mb + 2 * 2048);
    bf16* VbT = Xb;

    prep_k<<<4866, 256, 0, stream>>>(X, Wq, Wk, Wv, Wo, mask, Xb, WqT, WkT, WvT, WoT, rt, Mb, mflags);
    qkv_gemm<<<dim3(64, 24), 256, 0, stream>>>(Xb, WqT, WkT, WvT, bq, bk, bv, rt, Qb, Kb, Vb);
    vtrans_k<<<dim3(2, 64, 8), 256, 0, stream>>>((const unsigned short*)Vb, (unsigned short*)VbT);
    attn_k<<<dim3(16, 16, 2), 256, 0, stream>>>(Qb, Kb, VbT, Mb, mflags, Ab);
    oproj_gemm<<<dim3(64, 16), 256, 0, stream>>>(Ab, WoT, bo, out);
}

// Round 7
// 220.867 us; speedup vs baseline: 1.6744x; 1.0363x over previous
//
#include <hip/hip_runtime.h>

typedef __bf16 bf16;
typedef __attribute__((ext_vector_type(8))) __bf16 bf16x8;
typedef __attribute__((ext_vector_type(4))) __bf16 bf16x4;
typedef __attribute__((ext_vector_type(4))) float f32x4;

#define LOG2E 1.44269504088896340736f
#define QSCALE 0.18033688011112042f   // 0.125 * log2(e), folded into Q

// ---------------- Kernel P: fused prep ----------------
__device__ inline void tr_tile(const float* __restrict__ in, bf16* __restrict__ out,
                               int R, int C, int bx, int by, int tid) {
    __shared__ float t[32][33];
    int tx = tid & 31, ty = tid >> 5;
    int rbase = by * 32, cbase = bx * 32;
#pragma unroll
    for (int i = 0; i < 4; i++) {
        int r = ty + i * 8;
        t[r][tx] = in[(size_t)(rbase + r) * C + cbase + tx];
    }
    __syncthreads();
#pragma unroll
    for (int i = 0; i < 4; i++) {
        int r = ty + i * 8;
        out[(size_t)(cbase + r) * R + rbase + tx] = (bf16)t[tx][r];
    }
}

__global__ __launch_bounds__(256) void prep_k(const float* __restrict__ X,
                                              const float* __restrict__ Wq,
                                              const float* __restrict__ Wk,
                                              const float* __restrict__ Wv,
                                              const float* __restrict__ Wo,
                                              const float* __restrict__ mask,
                                              bf16* __restrict__ Xb,
                                              bf16* __restrict__ WqT,
                                              bf16* __restrict__ WkT,
                                              bf16* __restrict__ WvT,
                                              bf16* __restrict__ WoT,
                                              float2* __restrict__ rt,
                                              float* __restrict__ Mb,
                                              int* __restrict__ mflags) {
    int blk = blockIdx.x, tid = threadIdx.x;
    if (blk < 2048) {
        int idx = (blk * 256 + tid) * 8;
        float4 a = *(const float4*)(X + idx);
        float4 b = *(const float4*)(X + idx + 4);
        bf16 v[8] = {(bf16)a.x, (bf16)a.y, (bf16)a.z, (bf16)a.w,
                     (bf16)b.x, (bf16)b.y, (bf16)b.z, (bf16)b.w};
        *(uint4*)(Xb + idx) = *(const uint4*)v;
    } else if (blk < 3072) {
        int t = blk - 2048; tr_tile(Wq, WqT, 1024, 1024, t & 31, t >> 5, tid);
    } else if (blk < 3328) {
        int t = blk - 3072; tr_tile(Wk, WkT, 1024, 256, t & 7, t >> 3, tid);
    } else if (blk < 3584) {
        int t = blk - 3328; tr_tile(Wv, WvT, 1024, 256, t & 7, t >> 3, tid);
    } else if (blk < 4608) {
        int t = blk - 3584; tr_tile(Wo, WoT, 1024, 1024, t & 31, t >> 5, tid);
    } else if (blk < 4864) {
        int idx = (blk - 4608) * 256 + tid;  // idx = s*32 + i
        int s = idx >> 5, i = idx & 31;
        float inv = exp2f(-0.41524100370589830f * (float)i);  // 10000^(-i/32)
        float ang = (float)s * inv;
        rt[idx] = make_float2(cosf(ang), sinf(ang));
    } else {
        __shared__ int sflag;
        int b = blk - 4864;
        if (tid == 0) sflag = 1;
        __syncthreads();
        const float* mrow = mask + (size_t)b * 2048;
        int i0 = tid * 8;
        bool ones = true;
#pragma unroll
        for (int j = 0; j < 8; j++) {
            float m = mrow[i0 + j];
            if (m != 1.0f) ones = false;
            Mb[(size_t)b * 2048 + i0 + j] = (1.0f - m) * (-1e9f) * LOG2E;
        }
        if (!ones) sflag = 0;
        __syncthreads();
        if (tid == 0) mflags[b] = sflag;
    }
}

// ---------------- Kernel 0b: bf16 transpose per (b,kv): [2048][64] -> [64][2048] ----------------
__global__ __launch_bounds__(256) void vtrans_k(const unsigned short* __restrict__ in,
                                                unsigned short* __restrict__ out) {
    __shared__ unsigned short t[32][33];
    int z = blockIdx.z;
    const unsigned short* ip = in + (size_t)z * 2048 * 64;
    unsigned short* op = out + (size_t)z * 2048 * 64;
    int tx = threadIdx.x & 31, ty = threadIdx.x >> 5;
    int rbase = blockIdx.y * 32, cbase = blockIdx.x * 32;
#pragma unroll
    for (int i = 0; i < 4; i++) {
        int r = ty + i * 8;
        t[r][tx] = ip[(size_t)(rbase + r) * 64 + cbase + tx];
    }
    __syncthreads();
#pragma unroll
    for (int i = 0; i < 4; i++) {
        int r = ty + i * 8;
        op[(size_t)(cbase + r) * 2048 + rbase + tx] = t[tx][r];
    }
}

// ---------------- shared 128x128-tile GEMM mainloop (m97-style + xor k-swizzle) ----------------
// C[m0..m0+128)[n0..n0+128) = A[M][1024] @ BT[N][1024]^T, acc per wave 64x64 as 4x4 MFMA 16x16x32.
// LDS tiles As/Bs [128][64] bf16, k column xor-swizzled by (row&7)*8 to break bank conflicts.
__device__ __forceinline__ void gemm_main_128(const bf16* __restrict__ A,
                                              const bf16* __restrict__ BT,
                                              int m0, int n0, int tid,
                                              f32x4 (&acc)[4][4]) {
    __shared__ bf16 As[128 * 64];
    __shared__ bf16 Bs[128 * 64];
    int w = tid >> 6, lane = tid & 63, l15 = lane & 15, quad = lane >> 4;
    int wm = w >> 1, wn = w & 1;

    // staging: wave w covers rows [w*32, w*32+32) in 4 passes of 8 rows; lane l -> row
    // w*32+p*8+(l>>3), phys k chunk (l&7)*8 holding logical k ((l&7)^(l>>3))*8.
    int lrow = w * 32 + (lane >> 3);
    int kx = ((lane & 7) ^ (lane >> 3)) * 8;
    const bf16* ga0 = A + (size_t)(m0 + lrow) * 1024 + kx;
    const bf16* gb0 = BT + (size_t)(n0 + lrow) * 1024 + kx;
    bf16* la0 = As + w * 2048 + lane * 8;   // lane*16 bytes, wave-contiguous
    bf16* lb0 = Bs + w * 2048 + lane * 8;

    for (int k0 = 0; k0 < 1024; k0 += 64) {
#pragma unroll
        for (int p = 0; p < 4; p++) {
            __builtin_amdgcn_global_load_lds(
                (const __attribute__((address_space(1))) unsigned int*)(ga0 + (size_t)p * 8 * 1024 + k0),
                (__attribute__((address_space(3))) unsigned int*)(la0 + p * 512), 16, 0, 0);
            __builtin_amdgcn_global_load_lds(
                (const __attribute__((address_space(1))) unsigned int*)(gb0 + (size_t)p * 8 * 1024 + k0),
                (__attribute__((address_space(3))) unsigned int*)(lb0 + p * 512), 16, 0, 0);
        }
        __syncthreads();
#pragma unroll
        for (int kk = 0; kk < 64; kk += 32) {
            bf16x8 a[4], bfr[4];
            int kp = (kk + quad * 8) ^ ((l15 & 7) * 8);
#pragma unroll
            for (int i = 0; i < 4; i++)
                a[i] = *(const bf16x8*)&As[(wm * 64 + i * 16 + l15) * 64 + kp];
#pragma unroll
            for (int j = 0; j < 4; j++)
                bfr[j] = *(const bf16x8*)&Bs[(wn * 64 + j * 16 + l15) * 64 + kp];
#pragma unroll
            for (int i = 0; i < 4; i++)
#pragma unroll
                for (int j = 0; j < 4; j++)
                    acc[i][j] = __builtin_amdgcn_mfma_f32_16x16x32_bf16(a[i], bfr[j], acc[i][j], 0, 0, 0);
        }
        __syncthreads();
    }
}

// ---------------- Kernel 1: QKV GEMM (128-tile) + bias + RoPE + Q-prescale ----------------
// B = [WqT;WkT;WvT] contiguous [1536][1024]. grid (32, 12).
__global__ __launch_bounds__(256) void qkv_gemm2(const bf16* __restrict__ Xb,
                                                 const bf16* __restrict__ WTall,
                                                 const float* __restrict__ bq,
                                                 const float* __restrict__ bk,
                                                 const float* __restrict__ bv,
                                                 const float2* __restrict__ rt,
                                                 bf16* __restrict__ Qb,
                                                 bf16* __restrict__ Kb,
                                                 bf16* __restrict__ Vb) {
    int tt = blockIdx.x, nt = blockIdx.y, tid = threadIdx.x;
    f32x4 acc[4][4] = {};
    gemm_main_128(Xb, WTall, tt * 128, nt * 128, tid, acc);

    int w = tid >> 6, lane = tid & 63, l15 = lane & 15, quad = lane >> 4;
    int wm = w >> 1, wn = w & 1;
    int gy = nt * 2 + wn;  // 0..23
    const float* bias;
    bf16* dst;
    int mode, head;
    if (gy < 16)      { head = gy;      bias = bq + head * 64; dst = Qb; mode = 0; }
    else if (gy < 20) { head = gy - 16; bias = bk + head * 64; dst = Kb; mode = 1; }
    else              { head = gy - 20; bias = bv + head * 64; dst = Vb; mode = 2; }

#pragma unroll
    for (int i = 0; i < 4; i++) {
#pragma unroll
        for (int r = 0; r < 4; r++) {
            int token = tt * 128 + wm * 64 + i * 16 + quad * 4 + r;
            int b = token >> 11, s = token & 2047;
            float vals[4];
#pragma unroll
            for (int j = 0; j < 4; j++) vals[j] = acc[i][j][r] + bias[j * 16 + l15];
            if (mode <= 1) {  // RoPE via table
#pragma unroll
                for (int c = 0; c < 2; c++) {
                    float2 cs2 = rt[s * 32 + c * 16 + l15];
                    float x1 = vals[c], x2 = vals[c + 2];
                    vals[c]     = x1 * cs2.x - x2 * cs2.y;
                    vals[c + 2] = x1 * cs2.y + x2 * cs2.x;
                }
            }
            if (mode == 0) {
#pragma unroll
                for (int j = 0; j < 4; j++) vals[j] *= QSCALE;
            }
            size_t base;
            if (mode == 0) base = (((size_t)b * 16 + head) * 2048 + s) * 64;
            else           base = (((size_t)b * 4  + head) * 2048 + s) * 64;
#pragma unroll
            for (int j = 0; j < 4; j++) dst[base + j * 16 + l15] = (bf16)vals[j];
        }
    }
}

// ---------------- Kernel 3: O projection (128-tile, fp32 out). grid (32, 8). ----------------
__global__ __launch_bounds__(256) void oproj_gemm2(const bf16* __restrict__ Ab,
                                                   const bf16* __restrict__ WoT,
                                                   const float* __restrict__ bo,
                                                   float* __restrict__ out) {
    int tt = blockIdx.x, nt = blockIdx.y, tid = threadIdx.x;
    f32x4 acc[4][4] = {};
    gemm_main_128(Ab, WoT, tt * 128, nt * 128, tid, acc);

    int w = tid >> 6, lane = tid & 63, l15 = lane & 15, quad = lane >> 4;
    int wm = w >> 1, wn = w & 1;
#pragma unroll
    for (int i = 0; i < 4; i++) {
#pragma unroll
        for (int r = 0; r < 4; r++) {
            int token = tt * 128 + wm * 64 + i * 16 + quad * 4 + r;
#pragma unroll
            for (int j = 0; j < 4; j++) {
                int n = nt * 128 + wn * 64 + j * 16 + l15;
                out[(size_t)token * 1024 + n] = acc[i][j][r] + bo[n];
            }
        }
    }
}

// ---------------- Kernel 2: flash attention (S^T, LDS staging, 32q/wave) ----------------
__global__ __launch_bounds__(256) void attn_k(const bf16* __restrict__ Qb,
                                              const bf16* __restrict__ Kb,
                                              const bf16* __restrict__ VbT,
                                              const float* __restrict__ Mb,
                                              const int* __restrict__ mflags,
                                              bf16* __restrict__ Ob) {
    int qt = blockIdx.x, h = blockIdx.y, b = blockIdx.z;
    int kvh = h >> 2;  // rep = 4

    __shared__ unsigned short Ks[64 * 72];      // [key][d]
    __shared__ unsigned short Vs[64 * 72];      // [d][key] (from VbT)
    __shared__ unsigned short Ps[4][32 * 72];   // per-wave P [q(32)][key]

    int tid = threadIdx.x, w = tid >> 6, lane = tid & 63, l15 = lane & 15, quad = lane >> 4;

    const bool maskOnes = (mflags[b] != 0);

    bf16x8 qa[2][2];
#pragma unroll
    for (int g = 0; g < 2; g++) {
        size_t qbase = (((size_t)b * 16 + h) * 2048 + (size_t)qt * 128 + w * 32 + g * 16 + l15) * 64;
        qa[g][0] = *(const bf16x8*)(Qb + qbase + quad * 8);
        qa[g][1] = *(const bf16x8*)(Qb + qbase + 32 + quad * 8);
    }

    f32x4 oacc[2][4] = {};
    float m2[2] = {-1e30f, -1e30f}, lsum[2] = {0.f, 0.f};

    size_t kRow = ((size_t)b * 4 + kvh) * 2048;
    size_t vRow = ((size_t)b * 4 + kvh) * 64;
    const float* mrow = Mb + (size_t)b * 2048 + quad * 4;

    for (int kt = 0; kt < 32; kt++) {
#pragma unroll
        for (int it = 0; it < 2; it++) {
            int i = tid + it * 256;
            int row = i >> 3, cg = i & 7;
            uint4 kv4 = *(const uint4*)(Kb + (kRow + kt * 64 + row) * 64 + cg * 8);
            *(uint4*)&Ks[row * 72 + cg * 8] = kv4;
            uint4 vv4 = *(const uint4*)(VbT + (vRow + row) * 2048 + kt * 64 + cg * 8);
            *(uint4*)&Vs[row * 72 + cg * 8] = vv4;
        }
        __syncthreads();

        bf16x8 ka[4][2];
#pragma unroll
        for (int c = 0; c < 4; c++) {
            ka[c][0] = *(const bf16x8*)&Ks[(c * 16 + l15) * 72 + quad * 8];
            ka[c][1] = *(const bf16x8*)&Ks[(c * 16 + l15) * 72 + 32 + quad * 8];
        }

        f32x4 sc[2][4];
#pragma unroll
        for (int g = 0; g < 2; g++)
#pragma unroll
            for (int c = 0; c < 4; c++) {
                f32x4 z = {};
                z = __builtin_amdgcn_mfma_f32_16x16x32_bf16(ka[c][0], qa[g][0], z, 0, 0, 0);
                z = __builtin_amdgcn_mfma_f32_16x16x32_bf16(ka[c][1], qa[g][1], z, 0, 0, 0);
                sc[g][c] = z;
            }
        if (!maskOnes) {
#pragma unroll
            for (int c = 0; c < 4; c++) {
                f32x4 bias4 = *(const f32x4*)(mrow + kt * 64 + c * 16);
#pragma unroll
                for (int r = 0; r < 4; r++) { sc[0][c][r] += bias4[r]; sc[1][c][r] += bias4[r]; }
            }
        }

#pragma unroll
        for (int g = 0; g < 2; g++) {
            f32x4 m4 = sc[g][0];
#pragma unroll
            for (int c = 1; c < 4; c++)
#pragma unroll
                for (int r = 0; r < 4; r++) m4[r] = fmaxf(m4[r], sc[g][c][r]);
            float mx = fmaxf(fmaxf(m4[0], m4[1]), fmaxf(m4[2], m4[3]));
            mx = fmaxf(mx, __shfl_xor(mx, 16, 64));
            mx = fmaxf(mx, __shfl_xor(mx, 32, 64));

            if (__any(mx > m2[g])) {
                float mn = fmaxf(m2[g], mx);
                float alpha = exp2f(m2[g] - mn);
                m2[g] = mn;
                lsum[g] *= alpha;
                float alpha_r[4];
#pragma unroll
                for (int r = 0; r < 4; r++) alpha_r[r] = __shfl(alpha, quad * 4 + r, 64);
#pragma unroll
                for (int c = 0; c < 4; c++)
#pragma unroll
                    for (int r = 0; r < 4; r++) oacc[g][c][r] *= alpha_r[r];
            }

            float rs = 0.f;
#pragma unroll
            for (int c = 0; c < 4; c++)
#pragma unroll
                for (int r = 0; r < 4; r++) { sc[g][c][r] = exp2f(sc[g][c][r] - m2[g]); rs += sc[g][c][r]; }
            rs += __shfl_xor(rs, 16, 64);
            rs += __shfl_xor(rs, 32, 64);
            lsum[g] += rs;

#pragma unroll
            for (int c = 0; c < 4; c++) {
                bf16x4 pv = {(bf16)sc[g][c][0], (bf16)sc[g][c][1], (bf16)sc[g][c][2], (bf16)sc[g][c][3]};
                *(bf16x4*)&Ps[w][(g * 16 + l15) * 72 + c * 16 + quad * 4] = pv;
            }
        }

        bf16x8 vb[4][2];
#pragma unroll
        for (int c = 0; c < 4; c++) {
            vb[c][0] = *(const bf16x8*)&Vs[(c * 16 + l15) * 72 + quad * 8];
            vb[c][1] = *(const bf16x8*)&Vs[(c * 16 + l15) * 72 + 32 + quad * 8];
        }
        bf16x8 pa[2][2];
#pragma unroll
        for (int g = 0; g < 2; g++) {
            pa[g][0] = *(const bf16x8*)&Ps[w][(g * 16 + l15) * 72 + quad * 8];
            pa[g][1] = *(const bf16x8*)&Ps[w][(g * 16 + l15) * 72 + 32 + quad * 8];
        }
#pragma unroll
        for (int g = 0; g < 2; g++)
#pragma unroll
            for (int c = 0; c < 4; c++) {
                oacc[g][c] = __builtin_amdgcn_mfma_f32_16x16x32_bf16(pa[g][0], vb[c][0], oacc[g][c], 0, 0, 0);
                oacc[g][c] = __builtin_amdgcn_mfma_f32_16x16x32_bf16(pa[g][1], vb[c][1], oacc[g][c], 0, 0, 0);
            }
        __syncthreads();
    }

#pragma unroll
    for (int g = 0; g < 2; g++) {
        float linv[4];
#pragma unroll
        for (int r = 0; r < 4; r++) linv[r] = 1.0f / __shfl(lsum[g], quad * 4 + r, 64);
#pragma unroll
        for (int r = 0; r < 4; r++) {
            int q = qt * 128 + w * 32 + g * 16 + quad * 4 + r;
            size_t base = ((size_t)b * 2048 + q) * 1024 + h * 64;
#pragma unroll
            for (int c = 0; c < 4; c++) Ob[base + c * 16 + l15] = (bf16)(oacc[g][c][r] * linv[r]);
        }
    }
}

// ---------------- launch ----------------
extern "C" void kernel_launch(void* const* d_in, const int* in_sizes, int n_in,
                              void* d_out, int out_size, void* d_ws, size_t ws_size,
                              hipStream_t stream) {
    const float* X    = (const float*)d_in[0];
    const float* mask = (const float*)d_in[1];
    const float* Wq   = (const float*)d_in[2];
    const float* bq   = (const float*)d_in[3];
    const float* Wk   = (const float*)d_in[4];
    const float* bk   = (const float*)d_in[5];
    const float* Wv   = (const float*)d_in[6];
    const float* bv   = (const float*)d_in[7];
    const float* Wo   = (const float*)d_in[8];
    const float* bo   = (const float*)d_in[9];
    float* out = (float*)d_out;
    bf16* ws  = (bf16*)d_ws;

    bf16* Xb  = ws;                       // 4096x1024 (reused for VbT after qkv)
    bf16* WqT = Xb + (size_t)4096 * 1024; // [1024][1024]  -- WqT/WkT/WvT contiguous = [1536][1024]
    bf16* WkT = WqT + 1024 * 1024;        // [256][1024]
    bf16* WvT = WkT + 256 * 1024;         // [256][1024]
    bf16* WoT = WvT + 256 * 1024;         // [1024][1024]
    bf16* Qb  = WoT + 1024 * 1024;
    bf16* Kb  = Qb + (size_t)2 * 16 * 2048 * 64;
    bf16* Vb  = Kb + (size_t)2 * 4 * 2048 * 64;
    bf16* Ab  = Vb + (size_t)2 * 4 * 2048 * 64;
    float2* rt = (float2*)(Ab + (size_t)2 * 2048 * 1024);
    float* Mb  = (float*)(rt + 2048 * 32);
    int* mflags = (int*)(Mb + 2 * 2048);
    bf16* VbT = Xb;

    prep_k<<<4866, 256, 0, stream>>>(X, Wq, Wk, Wv, Wo, mask, Xb, WqT, WkT, WvT, WoT, rt, Mb, mflags);
    qkv_gemm2<<<dim3(32, 12), 256, 0, stream>>>(Xb, WqT, bq, bk, bv, rt, Qb, Kb, Vb);
    vtrans_k<<<dim3(2, 64, 8), 256, 0, stream>>>((const unsigned short*)Vb, (unsigned short*)VbT);
    attn_k<<<dim3(16, 16, 2), 256, 0, stream>>>(Qb, Kb, VbT, Mb, mflags, Ab);
    oproj_gemm2<<<dim3(32, 8), 256, 0, stream>>>(Ab, WoT, bo, out);
}